// Round 20
// baseline (1438.757 us; speedup 1.0000x reference)
//
#include <hip/hip_runtime.h>
#include <math.h>

typedef unsigned short u16;
typedef unsigned int   u32;
typedef __attribute__((ext_vector_type(4))) float f32x4;
typedef __attribute__((ext_vector_type(8))) short bf16x8;   // 8 bf16 for MFMA frag
typedef __attribute__((ext_vector_type(8))) u16   u16x8;
typedef __attribute__((ext_vector_type(4))) u16   u16x4;
typedef __attribute__((ext_vector_type(2))) u32   u32x2;
typedef _Float16 h2 __attribute__((ext_vector_type(2)));

#define DEVI static __device__ __forceinline__

DEVI float bf2f(u16 a){ u32 u=((u32)a)<<16; float f; __builtin_memcpy(&f,&u,4); return f; }
DEVI u16 f2bf(float f){ u32 u; __builtin_memcpy(&u,&f,4); u=u+0x7fffu+((u>>16)&1u); return (u16)(u>>16); }
DEVI h2 pkh(float a, float b){
  auto t = __builtin_amdgcn_cvt_pkrtz(a, b);   // __fp16 ext-vector(2)
  h2 r; __builtin_memcpy(&r, &t, 4); return r; // bit-identical, type-cast only
}
DEVI h2 asH2(u32 u){ h2 r; __builtin_memcpy(&r,&u,4); return r; }
DEVI u32 asU32(h2 x){ u32 r; __builtin_memcpy(&r,&x,4); return r; }

// async global->LDS 16B: dest = wave-uniform base + lane*16; src is per-lane.
DEVI void gload16(const u16* src, u16* lds){
  __builtin_amdgcn_global_load_lds((const __attribute__((address_space(1))) u32*)src,
                                   (__attribute__((address_space(3))) u32*)lds, 16, 0, 0);
}

// ---------------- tiny prep kernels ----------------
__global__ void k_wvt(const float* __restrict__ Wv, u16* __restrict__ WvT){
  int n = blockIdx.x;
  for (int k = threadIdx.x; k < 512; k += 256)
    WvT[(size_t)n*512 + k] = f2bf(Wv[(size_t)k*512 + n]);
}
__global__ void k_wrep(const float* __restrict__ w1, const float* __restrict__ w2, float* __restrict__ wt){
  int s = blockIdx.x/9, tap = blockIdx.x%9, c = threadIdx.x;
  const float* w = s ? w2 : w1;
  wt[(size_t)(s*9+tap)*512 + c] = w[(size_t)c*9 + tap];
}

// ---------------- K1: v = x @ Wv (bf16), also emits xbT = bf16(x)^T ----------------
// grid 2048, block 512 (8 waves, each wave-tile 128x64), BK=32, dbuf 80KB LDS.
__global__ __launch_bounds__(512) void k_gemm_v(const float* __restrict__ x, const u16* __restrict__ WvT,
                                                u16* __restrict__ v, u16* __restrict__ xbT){
  extern __shared__ __align__(16) u16 sm[];   // A0[4096] A1[4096] B0[16384] B1[16384] u16
  const int tid = threadIdx.x;
  const int l = tid & 63, w = tid >> 6;       // 8 waves, wave w owns cols w*64..w*64+63
  const long r0 = (long)blockIdx.x * 128;
  f32x4 acc[8][4] = {};

  const int arow = tid >> 2, ac = tid & 3;    // A stage: row 0..127, k-chunk 0..3
  const float* xp = x + (r0 + arow)*512 + ac*8;
  f32x4 rAa, rAb;

  auto LOADA = [&](int kk){ rAa = *(const f32x4*)(xp + kk); rAb = *(const f32x4*)(xp + kk + 4); };
  auto WRITEA = [&](int buf){
    u16x8 o;
    o[0]=f2bf(rAa.x); o[1]=f2bf(rAa.y); o[2]=f2bf(rAa.z); o[3]=f2bf(rAa.w);
    o[4]=f2bf(rAb.x); o[5]=f2bf(rAb.y); o[6]=f2bf(rAb.z); o[7]=f2bf(rAb.w);
    *(u16x8*)&sm[buf*4096 + arow*32 + ((ac ^ ((arow>>1)&3))*8)] = o;
  };
  auto GLOADB = [&](int buf, int kk){
    #pragma unroll
    for (int i = 0; i < 4; ++i){
      int blkrow = w*64 + i*16;
      int r = blkrow + (l>>2);
      const u16* src = WvT + (size_t)r*512 + kk + (((l&3) ^ ((l>>3)&3))*8);
      gload16(src, &sm[8192 + buf*16384 + blkrow*32]);
    }
  };

  LOADA(0); WRITEA(0); LOADA(32); GLOADB(0, 0);
  __syncthreads();
  for (int t = 0; t < 16; ++t){
    const int cur = t & 1;
    if (t < 15){
      WRITEA(cur^1);
      if (t < 14) LOADA((t+2)*32);
      GLOADB(cur^1, (t+1)*32);
    }
    const u16* Al = sm + cur*4096;
    const u16* Bl = sm + 8192 + cur*16384;
    bf16x8 bfr[4];
    #pragma unroll
    for (int nf = 0; nf < 4; ++nf){
      int row = w*64 + nf*16 + (l&15);
      bfr[nf] = *(const bf16x8*)&Bl[row*32 + (((l>>4) ^ ((row>>1)&3))*8)];
    }
    #pragma unroll
    for (int mf = 0; mf < 8; ++mf){
      int row = mf*16 + (l&15);
      bf16x8 af = *(const bf16x8*)&Al[row*32 + (((l>>4) ^ ((row>>1)&3))*8)];
      #pragma unroll
      for (int nf = 0; nf < 4; ++nf)
        acc[mf][nf] = __builtin_amdgcn_mfma_f32_16x16x32_bf16(af, bfr[nf], acc[mf][nf], 0,0,0);
    }
    { // xbT write for this K-step from Al: [ch 32][tok 128]
      int chloc = tid & 31, tg = tid >> 5;    // 16 groups x 8 tok
      u16x8 o;
      #pragma unroll
      for (int j = 0; j < 8; ++j){
        int tok = tg*8 + j;
        o[j] = Al[tok*32 + (((chloc>>3) ^ ((tok>>1)&3))*8) + (chloc&7)];
      }
      *(u16x8*)(xbT + (size_t)(t*32 + chloc)*262144 + r0 + tg*8) = o;
    }
    __syncthreads();
  }
  #pragma unroll
  for (int mf = 0; mf < 8; ++mf)
    #pragma unroll
    for (int nf = 0; nf < 4; ++nf){
      int col = w*64 + nf*16 + (l&15);
      #pragma unroll
      for (int j = 0; j < 4; ++j){
        long row = r0 + mf*16 + (l>>4)*4 + j;
        v[(size_t)row*512 + col] = f2bf(acc[mf][nf][j]);
      }
    }
}

// ---------------- K0: S partials = X^T X from xbT (v3: BK=32, 64KB -> 2 blk/CU) --
// grid 768 = b(4)*combo(3)*csplit(64); block 512 (8 waves 2x4 -> 128x64 tiles),
// BK=32 double-buffered 64KB dynamic LDS, prefetch-before-compute.
__global__ __launch_bounds__(512) void k_syrk(const u16* __restrict__ xbT, float* __restrict__ P){
  extern __shared__ __align__(16) u16 sm[];   // A0 @0, A1 @8192, B0 @16384, B1 @24576 (u16)
  const int bid = blockIdx.x;
  const int cs = bid & 63, combo = (bid>>6)%3, b = bid/192;
  const int hA = (combo==2) ? 1 : 0;
  const int tid = threadIdx.x;
  const int l = tid & 63, w = tid >> 6;
  const int wi = w >> 2, wj = w & 3;          // wave tile 128 rows x 64 cols
  const long tokb0 = (long)b*65536 + (long)cs*1024;
  f32x4 acc[8][4] = {};

  auto STAGE = [&](int buf, long tokb){
    u16* Ab = sm + buf*8192;
    #pragma unroll
    for (int i = 0; i < 2; ++i){              // A: 256 rows x 32 tok, 2 gloads/wave
      int blkrow = w*32 + i*16;
      int r = blkrow + (l>>2);
      gload16(xbT + (size_t)(hA*256 + r)*262144 + tokb + (((l&3) ^ ((l>>3)&3))*8),
              Ab + blkrow*32);
    }
    if (combo == 1){
      u16* Bb = sm + 16384 + buf*8192;
      #pragma unroll
      for (int i = 0; i < 2; ++i){
        int blkrow = w*32 + i*16;
        int r = blkrow + (l>>2);
        gload16(xbT + (size_t)(256 + r)*262144 + tokb + (((l&3) ^ ((l>>3)&3))*8),
                Bb + blkrow*32);
      }
    }
  };

  STAGE(0, tokb0);
  __syncthreads();
  for (int t = 0; t < 32; ++t){
    const int cur = t & 1;
    if (t < 31) STAGE(cur^1, tokb0 + (t+1)*32);
    const u16* Al = sm + cur*8192;
    const u16* Bl = (combo==1) ? (sm + 16384 + cur*8192) : Al;
    bf16x8 bfr[4];
    #pragma unroll
    for (int nf = 0; nf < 4; ++nf){
      int row = wj*64 + nf*16 + (l&15);
      bfr[nf] = *(const bf16x8*)&Bl[row*32 + (((l>>4) ^ ((row>>1)&3))*8)];
    }
    #pragma unroll
    for (int mf = 0; mf < 8; ++mf){
      int row = wi*128 + mf*16 + (l&15);
      bf16x8 af = *(const bf16x8*)&Al[row*32 + (((l>>4) ^ ((row>>1)&3))*8)];
      #pragma unroll
      for (int nf = 0; nf < 4; ++nf)
        acc[mf][nf] = __builtin_amdgcn_mfma_f32_16x16x32_bf16(af, bfr[nf], acc[mf][nf], 0,0,0);
    }
    __syncthreads();
  }
  float* Pb = P + (size_t)bid*65536;
  #pragma unroll
  for (int mf = 0; mf < 8; ++mf)
    #pragma unroll
    for (int nf = 0; nf < 4; ++nf)
      #pragma unroll
      for (int j = 0; j < 4; ++j){
        int il = wi*128 + mf*16 + (l>>4)*4 + j;
        int jl = wj*64 + nf*16 + (l&15);
        Pb[il*256 + jl] = acc[mf][nf][j];
      }
}

// reduce partials -> S[b][512][512]
__global__ void k_sred(const float* __restrict__ P, float* __restrict__ S){
  int bid = blockIdx.x;               // 3072 = 4*3*256
  int il = bid & 255, combo = (bid>>8)%3, b = bid/768;
  int hi = (combo==2)?1:0, hj = (combo==0)?0:1;
  int jl = threadIdx.x;
  float s = 0.f;
  for (int cs = 0; cs < 64; ++cs)
    s += P[((size_t)(b*192 + combo*64 + cs))*65536 + il*256 + jl];
  int I = hi*256 + il, J = hj*256 + jl;
  S[((size_t)b*512 + I)*512 + J] = s;
  if (combo == 1) S[((size_t)b*512 + J)*512 + I] = s;
}

// ---------------- tiny algebra chain ----------------
__global__ __launch_bounds__(256) void k_a1(const float* __restrict__ S, const float* __restrict__ Wq,
                                            const float* __restrict__ Wk, float* __restrict__ T, float* __restrict__ U){
  int bid = blockIdx.x;
  int b = bid>>6, rem = bid&63, which = rem>>5, rbase = (rem&31)*16;
  const float* W = which ? Wk : Wq;
  float* O = which ? U : T;
  int tid = threadIdx.x;
  int rg = tid>>6, c0 = (tid&63)*8;
  const float* Sr = S + (size_t)b*262144 + (size_t)(rbase + rg*4)*512;
  float acc[4][8] = {};
  for (int k = 0; k < 512; ++k){
    float s0 = Sr[k], s1 = Sr[512+k], s2 = Sr[1024+k], s3 = Sr[1536+k];
    f32x4 wa = *(const f32x4*)(W + (size_t)k*512 + c0);
    f32x4 wb = *(const f32x4*)(W + (size_t)k*512 + c0 + 4);
    #pragma unroll
    for (int j = 0; j < 4; ++j){
      acc[0][j]   += s0*wa[j]; acc[1][j]   += s1*wa[j]; acc[2][j]   += s2*wa[j]; acc[3][j]   += s3*wa[j];
      acc[0][4+j] += s0*wb[j]; acc[1][4+j] += s1*wb[j]; acc[2][4+j] += s2*wb[j]; acc[3][4+j] += s3*wb[j];
    }
  }
  float* Ob = O + (size_t)b*262144;
  #pragma unroll
  for (int i = 0; i < 4; ++i){
    f32x4 o0, o1;
    o0.x=acc[i][0]; o0.y=acc[i][1]; o0.z=acc[i][2]; o0.w=acc[i][3];
    o1.x=acc[i][4]; o1.y=acc[i][5]; o1.z=acc[i][6]; o1.w=acc[i][7];
    *(f32x4*)(Ob + (size_t)(rbase+rg*4+i)*512 + c0)     = o0;
    *(f32x4*)(Ob + (size_t)(rbase+rg*4+i)*512 + c0 + 4) = o1;
  }
}

__global__ void k_a2(const float* __restrict__ Wq, const float* __restrict__ Wk,
                     const float* __restrict__ T, const float* __restrict__ U,
                     float* __restrict__ G, float* __restrict__ q2, float* __restrict__ k2){
  int b = blockIdx.x>>3, h = blockIdx.x&7;
  int tid = threadIdx.x;
  int d0 = (tid>>4)*4, e0 = (tid&15)*4;
  const float* Tb = T + (size_t)b*262144;
  float acc[4][4] = {};
  for (int i = 0; i < 512; ++i){
    f32x4 wk = *(const f32x4*)(Wk + (size_t)i*512 + h*64 + d0);
    f32x4 tv = *(const f32x4*)(Tb + (size_t)i*512 + h*64 + e0);
    #pragma unroll
    for (int di = 0; di < 4; ++di)
      #pragma unroll
      for (int ej = 0; ej < 4; ++ej) acc[di][ej] += wk[di]*tv[ej];
  }
  float* Gb = G + ((size_t)(b*8+h))*4096;
  #pragma unroll
  for (int di = 0; di < 4; ++di)
    #pragma unroll
    for (int ej = 0; ej < 4; ++ej) Gb[(d0+di)*64 + e0+ej] = acc[di][ej];
  if (tid < 64){
    int e = tid; float a = 0.f;
    for (int j = 0; j < 512; ++j) a += Wq[(size_t)j*512 + h*64 + e] * Tb[(size_t)j*512 + h*64 + e];
    q2[b*512 + h*64 + e] = a;
  } else if (tid < 128){
    int d = tid - 64; float a = 0.f;
    const float* Ub = U + (size_t)b*262144;
    for (int j = 0; j < 512; ++j) a += Wk[(size_t)j*512 + h*64 + d] * Ub[(size_t)j*512 + h*64 + d];
    k2[b*512 + h*64 + d] = a;
  }
}

__global__ void k_a3(const float* __restrict__ G, const float* __restrict__ resc,
                     const float* __restrict__ q2, const float* __restrict__ k2, float* __restrict__ Aa){
  int b = blockIdx.x>>3, h = blockIdx.x&7;
  int d = threadIdx.x;
  const float* g = G + ((size_t)(b*8+h))*4096 + d*64;
  float kn = fmaxf(sqrtf(k2[b*512 + h*64 + d]), 1e-12f);
  float sc = resc[h] / kn;
  float m = -3.4e38f;
  for (int e = 0; e < 64; ++e){
    float qn = fmaxf(sqrtf(q2[b*512 + h*64 + e]), 1e-12f);
    m = fmaxf(m, g[e]*sc/qn);
  }
  float ssum = 0.f;
  for (int e = 0; e < 64; ++e){
    float qn = fmaxf(sqrtf(q2[b*512 + h*64 + e]), 1e-12f);
    ssum += expf(g[e]*sc/qn - m);
  }
  float inv = 1.0f/ssum;
  float* ao = Aa + ((size_t)(b*8+h))*4096 + d*64;
  for (int e = 0; e < 64; ++e){
    float qn = fmaxf(sqrtf(q2[b*512 + h*64 + e]), 1e-12f);
    ao[e] = expf(g[e]*sc/qn - m)*inv;
  }
}

__global__ void k_a4(const float* __restrict__ Aa, const float* __restrict__ pw, u16* __restrict__ MT){
  int bid = blockIdx.x;
  int jt = bid&3, h = (bid>>2)&7, b = bid>>5;
  int tid = threadIdx.x;
  int j = jt*128 + (tid&127), eh = tid>>7;
  const float* Ab = Aa + ((size_t)(b*8+h))*4096;
  float acc[32] = {};
  for (int d = 0; d < 64; ++d){
    float p = pw[(size_t)(h*64+d)*512 + j];
    const float* ar = Ab + d*64 + eh*32;
    #pragma unroll
    for (int q = 0; q < 8; ++q){
      f32x4 pa = *(const f32x4*)(ar + q*4);
      acc[q*4+0] += pa.x*p; acc[q*4+1] += pa.y*p; acc[q*4+2] += pa.z*p; acc[q*4+3] += pa.w*p;
    }
  }
  u16* mo = MT + (size_t)b*262144 + (size_t)j*512 + h*64 + eh*32;
  #pragma unroll
  for (int q = 0; q < 16; ++q){
    u32 pk = (u32)f2bf(acc[2*q]) | ((u32)f2bf(acc[2*q+1])<<16);
    *(u32*)&mo[2*q] = pk;
  }
}

// ---------------- fused conv v8 (R19, 314us): R15 structure + packed-f16 math ----
// grid 32768 = b(4)*ty(16)*tx(16)*chgrp(32); block 256; LDS 29KB -> 5 blk/CU.
__global__ __launch_bounds__(256) void k_conv_fused(const u16* __restrict__ v, const float* __restrict__ wt,
                                                    u16* __restrict__ cbuf){
  __shared__ __align__(16) u16 vtf[400*20];   // 20x20 spatial x (16ch + 4 pad) f16 bits
  __shared__ __align__(16) u16 t1f[324*20];   // 18x18 spatial x (16ch + 4 pad) f16 bits
  const int logical = (blockIdx.x & 7)*4096 + (blockIdx.x >> 3);  // XCD-chunked
  const int g = logical & 31, tx = (logical>>5)&15, ty = (logical>>9)&15, b = logical>>13;
  const int c0 = g*16, oy0 = ty*16, ox0 = tx*16;
  const int tid = threadIdx.x;
  const int quad = tid & 3;

  // stage v 20x20x16 -> f16 LDS (bf16->f32->pk f16), zero outside image
  for (int k = 0; k < 7; ++k){
    int q = tid + k*256; if (q >= 1600) break;
    int pos = q >> 2;
    int ly = pos / 20, lx = pos - ly*20;
    int gy = oy0 - 2 + ly, gx = ox0 - 2 + lx;
    u32x2 st = {};
    if (gy >= 0 && gy < 256 && gx >= 0 && gx < 256){
      u16x4 raw = *(const u16x4*)(v + ((size_t)(b*65536 + gy*256 + gx))*512 + c0 + quad*4);
      st.x = asU32(pkh(bf2f(raw[0]), bf2f(raw[1])));
      st.y = asU32(pkh(bf2f(raw[2]), bf2f(raw[3])));
    }
    *(u32x2*)&vtf[pos*20 + quad*4] = st;
  }

  h2 wql[9], wqh[9];
  #pragma unroll
  for (int tap = 0; tap < 9; ++tap){
    f32x4 wf = *(const f32x4*)(wt + (size_t)tap*512 + c0 + quad*4);
    wql[tap] = pkh(wf.x, wf.y); wqh[tap] = pkh(wf.z, wf.w);
  }
  __syncthreads();

  // conv1+gelu on 18x18, y-blocked (4 outputs/task over 6 rows x 3 cols).
  for (int task = tid; task < 1440; task += 256){
    int tq = task & 3;                  // == quad
    int rest = task >> 2;
    if (rest >= 90) break;
    int x1 = rest % 18, ychunk = rest / 18;
    int y1b = ychunk*4;
    h2 accl[4] = {}, acch[4] = {};
    #pragma unroll
    for (int rr = 0; rr < 6; ++rr){
      int yr = y1b + rr; yr = yr > 19 ? 19 : yr;   // clamp feeds only unstored outputs
      u32x2 r0 = *(const u32x2*)&vtf[(yr*20 + x1    )*20 + tq*4];
      u32x2 r1 = *(const u32x2*)&vtf[(yr*20 + x1 + 1)*20 + tq*4];
      u32x2 r2 = *(const u32x2*)&vtf[(yr*20 + x1 + 2)*20 + tq*4];
      h2 a0l = asH2(r0.x), a0h = asH2(r0.y);
      h2 a1l = asH2(r1.x), a1h = asH2(r1.y);
      h2 a2l = asH2(r2.x), a2h = asH2(r2.y);
      #pragma unroll
      for (int oy = 0; oy < 4; ++oy){
        int dy = rr - oy;
        if (dy >= 0 && dy < 3){
          accl[oy] += a0l*wql[dy*3+0] + a1l*wql[dy*3+1] + a2l*wql[dy*3+2];
          acch[oy] += a0h*wqh[dy*3+0] + a1h*wqh[dy*3+1] + a2h*wqh[dy*3+2];
        }
      }
    }
    #pragma unroll
    for (int oy = 0; oy < 4; ++oy){
      int y1 = y1b + oy;
      if (y1 < 18){
        int gy1 = oy0 - 1 + y1, gx1 = ox0 - 1 + x1;
        bool inimg = (gy1 >= 0 && gy1 < 256 && gx1 >= 0 && gx1 < 256);
        float a0 = (float)accl[oy][0], a1 = (float)accl[oy][1];
        float a2 = (float)acch[oy][0], a3 = (float)acch[oy][1];
        float g0 = a0 / (1.0f + __expf(-1.5957691216f*a0*(1.0f + 0.044715f*a0*a0)));
        float g1 = a1 / (1.0f + __expf(-1.5957691216f*a1*(1.0f + 0.044715f*a1*a1)));
        float g2 = a2 / (1.0f + __expf(-1.5957691216f*a2*(1.0f + 0.044715f*a2*a2)));
        float g3 = a3 / (1.0f + __expf(-1.5957691216f*a3*(1.0f + 0.044715f*a3*a3)));
        u32x2 st = {};
        if (inimg){ st.x = asU32(pkh(g0, g1)); st.y = asU32(pkh(g2, g3)); }
        *(u32x2*)&t1f[(y1*18 + x1)*20 + tq*4] = st;
      }
    }
  }

  #pragma unroll
  for (int tap = 0; tap < 9; ++tap){
    f32x4 wf = *(const f32x4*)(wt + (size_t)(9+tap)*512 + c0 + quad*4);
    wql[tap] = pkh(wf.x, wf.y); wqh[tap] = pkh(wf.z, wf.w);
  }
  __syncthreads();

  // conv2 on 16x16, y-blocked: exactly 256 tasks = x2(16, fastest) x ychunk(4) x quad
  {
    int rest = tid >> 2;                // quad == tid&3
    int x2 = rest & 15, ychunk = rest >> 4;
    int y2b = ychunk*4;
    h2 accl[4] = {}, acch[4] = {};
    #pragma unroll
    for (int rr = 0; rr < 6; ++rr){
      int yr = y2b + rr;                // max 12+5=17 <= 17: in range
      u32x2 r0 = *(const u32x2*)&t1f[(yr*18 + x2    )*20 + quad*4];
      u32x2 r1 = *(const u32x2*)&t1f[(yr*18 + x2 + 1)*20 + quad*4];
      u32x2 r2 = *(const u32x2*)&t1f[(yr*18 + x2 + 2)*20 + quad*4];
      h2 a0l = asH2(r0.x), a0h = asH2(r0.y);
      h2 a1l = asH2(r1.x), a1h = asH2(r1.y);
      h2 a2l = asH2(r2.x), a2h = asH2(r2.y);
      #pragma unroll
      for (int oy = 0; oy < 4; ++oy){
        int dy = rr - oy;
        if (dy >= 0 && dy < 3){
          accl[oy] += a0l*wql[dy*3+0] + a1l*wql[dy*3+1] + a2l*wql[dy*3+2];
          acch[oy] += a0h*wqh[dy*3+0] + a1h*wqh[dy*3+1] + a2h*wqh[dy*3+2];
        }
      }
    }
    #pragma unroll
    for (int oy = 0; oy < 4; ++oy){
      u16x4 o;
      o[0] = f2bf((float)accl[oy][0]); o[1] = f2bf((float)accl[oy][1]);
      o[2] = f2bf((float)acch[oy][0]); o[3] = f2bf((float)acch[oy][1]);
      size_t tok = (size_t)b*65536 + (size_t)(oy0 + y2b + oy)*256 + (ox0 + x2);
      *(u16x4*)(cbuf + tok*512 + c0 + quad*4) = o;
    }
  }
}

// ---------------- K4: out = v @ M[b] + pb + cbuf ----------------
// 256x256 block tile, 512 thr = 8 waves of 128x64, BK=64,
// double-buffered 128KB dynamic LDS, prefetch-before-compute.
__global__ __launch_bounds__(512, 2) void k_gemm_out(const u16* __restrict__ v, const u16* __restrict__ MT,
                                                     const float* __restrict__ proj_b, const u16* __restrict__ cbuf,
                                                     float* __restrict__ out){
  extern __shared__ __align__(16) u16 sm[];
  const int tid = threadIdx.x;
  const int l = tid & 63, w = tid >> 6;       // 8 waves
  const int wr = w >> 2, wc = w & 3;          // 2 x 4 -> wave tile 128x64
  const int bid = blockIdx.x;
  const int wg = (bid & 7)*256 + (bid >> 3);  // XCD-contiguous chunks (bijective)
  const long r0 = (long)(wg >> 1) * 256;
  const int  c0b = (wg & 1) * 256;
  const int  b = (int)(r0 >> 16);
  const u16* Mb = MT + (size_t)b*262144;
  f32x4 acc[8][4] = {};

  auto STAGE = [&](int buf, int k0){
    u16* Ab = sm + buf*16384;
    u16* Bb = sm + 32768 + buf*16384;
    #pragma unroll
    for (int i = 0; i < 4; ++i){
      int blkrow = w*32 + i*8;
      int r = blkrow + (l>>3);
      gload16(v + (size_t)(r0 + r)*512 + k0 + (((l&7) ^ (r&7))*8), Ab + blkrow*64);
    }
    #pragma unroll
    for (int i = 0; i < 4; ++i){
      int blkrow = w*32 + i*8;
      int r = blkrow + (l>>3);
      gload16(Mb + (size_t)(c0b + r)*512 + k0 + (((l&7) ^ (r&7))*8), Bb + blkrow*64);
    }
  };

  STAGE(0, 0);
  __syncthreads();
  for (int t = 0; t < 8; ++t){
    const int cur = t & 1;
    if (t < 7) STAGE(cur^1, (t+1)*64);
    const u16* Al = sm + cur*16384;
    const u16* Bl = sm + 32768 + cur*16384;
    #pragma unroll
    for (int ks = 0; ks < 2; ++ks){
      bf16x8 bfr[4];
      #pragma unroll
      for (int nf = 0; nf < 4; ++nf){
        int row = wc*64 + nf*16 + (l&15);
        bfr[nf] = *(const bf16x8*)&Bl[row*64 + (((ks*4 + (l>>4)) ^ (row&7))*8)];
      }
      #pragma unroll
      for (int mf = 0; mf < 8; ++mf){
        int row = wr*128 + mf*16 + (l&15);
        bf16x8 af = *(const bf16x8*)&Al[row*64 + (((ks*4 + (l>>4)) ^ (row&7))*8)];
        #pragma unroll
        for (int nf = 0; nf < 4; ++nf)
          acc[mf][nf] = __builtin_amdgcn_mfma_f32_16x16x32_bf16(af, bfr[nf], acc[mf][nf], 0,0,0);
      }
    }
    __syncthreads();
  }
  #pragma unroll
  for (int mf = 0; mf < 8; ++mf)
    #pragma unroll
    for (int nf = 0; nf < 4; ++nf){
      int col = c0b + wc*64 + nf*16 + (l&15);
      float pb = proj_b[col];
      #pragma unroll
      for (int j = 0; j < 4; ++j){
        long row = r0 + wr*128 + mf*16 + (l>>4)*4 + j;
        out[(size_t)row*512 + col] = acc[mf][nf][j] + pb + bf2f(cbuf[(size_t)row*512 + col]);
      }
    }
}

// ---------------- host ----------------
extern "C" void kernel_launch(void* const* d_in, const int* in_sizes, int n_in,
                              void* d_out, int out_size, void* d_ws, size_t ws_size,
                              hipStream_t stream){
  const float* x   = (const float*)d_in[0];
  const float* Wq  = (const float*)d_in[1];
  const float* Wk  = (const float*)d_in[2];
  const float* Wv  = (const float*)d_in[3];
  const float* rsc = (const float*)d_in[4];
  const float* pw  = (const float*)d_in[5];
  const float* pb  = (const float*)d_in[6];
  const float* w1  = (const float*)d_in[7];
  const float* w2  = (const float*)d_in[8];
  float* out = (float*)d_out;
  char* ws = (char*)d_ws;

  const size_t MB256 = 268435456;
  u16*   v    = (u16*)ws;                   // 256MB, live whole call
  u16*   xbT  = (u16*)(ws + MB256);         // 256MB, dead after k_syrk
  u16*   cbuf = xbT;                        // aliases xbT (conv runs after syrk)
  char*  sm0  = ws + 2*MB256;
  float* P    = (float*)d_out;              // 192MB partials in d_out (dead before out written)

  float* S   = (float*)(sm0);
  float* Tm  = (float*)(sm0 + 4194304);
  float* Um  = (float*)(sm0 + 8388608);
  float* G   = (float*)(sm0 + 12582912);
  float* Aa  = (float*)(sm0 + 13107200);
  float* q2  = (float*)(sm0 + 13631488);
  float* k2  = (float*)(sm0 + 13639680);
  u16*   MT  = (u16*)  (sm0 + 13647872);
  u16*   WvT = (u16*)  (sm0 + 15745024);
  float* wt  = (float*)(sm0 + 16269312);

  k_wvt <<<512, 256, 0, stream>>>(Wv, WvT);
  k_wrep<<<18, 512, 0, stream>>>(w1, w2, wt);
  k_gemm_v<<<2048, 512, 81920, stream>>>(x, WvT, v, xbT);
  k_syrk<<<768, 512, 65536, stream>>>(xbT, P);
  k_sred<<<3072, 256, 0, stream>>>(P, S);
  k_a1<<<256, 256, 0, stream>>>(S, Wq, Wk, Tm, Um);
  k_a2<<<32, 256, 0, stream>>>(Wq, Wk, Tm, Um, G, q2, k2);
  k_a3<<<32, 64, 0, stream>>>(G, rsc, q2, k2, Aa);
  k_a4<<<128, 256, 0, stream>>>(Aa, pw, MT);
  k_conv_fused<<<32768, 256, 0, stream>>>(v, wt, cbuf);
  k_gemm_out<<<2048, 512, 131072, stream>>>(v, MT, pb, cbuf, out);
}

// Round 21
// 1423.880 us; speedup vs baseline: 1.0104x; 1.0104x over previous
//
#include <hip/hip_runtime.h>
#include <math.h>

typedef unsigned short u16;
typedef unsigned int   u32;
typedef __attribute__((ext_vector_type(4))) float f32x4;
typedef __attribute__((ext_vector_type(8))) short bf16x8;   // 8 bf16 for MFMA frag
typedef __attribute__((ext_vector_type(8))) u16   u16x8;
typedef __attribute__((ext_vector_type(4))) u16   u16x4;
typedef __attribute__((ext_vector_type(2))) u32   u32x2;
typedef _Float16 h2 __attribute__((ext_vector_type(2)));

#define DEVI static __device__ __forceinline__

DEVI float bf2f(u16 a){ u32 u=((u32)a)<<16; float f; __builtin_memcpy(&f,&u,4); return f; }
DEVI u16 f2bf(float f){ u32 u; __builtin_memcpy(&u,&f,4); u=u+0x7fffu+((u>>16)&1u); return (u16)(u>>16); }
DEVI h2 pkh(float a, float b){
  auto t = __builtin_amdgcn_cvt_pkrtz(a, b);   // __fp16 ext-vector(2)
  h2 r; __builtin_memcpy(&r, &t, 4); return r; // bit-identical, type-cast only
}
DEVI h2 asH2(u32 u){ h2 r; __builtin_memcpy(&r,&u,4); return r; }
DEVI u32 asU32(h2 x){ u32 r; __builtin_memcpy(&r,&x,4); return r; }

// async global->LDS 16B: dest = wave-uniform base + lane*16; src is per-lane.
DEVI void gload16(const u16* src, u16* lds){
  __builtin_amdgcn_global_load_lds((const __attribute__((address_space(1))) u32*)src,
                                   (__attribute__((address_space(3))) u32*)lds, 16, 0, 0);
}

// ---------------- tiny prep kernels ----------------
__global__ void k_wvt(const float* __restrict__ Wv, u16* __restrict__ WvT){
  int n = blockIdx.x;
  for (int k = threadIdx.x; k < 512; k += 256)
    WvT[(size_t)n*512 + k] = f2bf(Wv[(size_t)k*512 + n]);
}
__global__ void k_wrep(const float* __restrict__ w1, const float* __restrict__ w2, float* __restrict__ wt){
  int s = blockIdx.x/9, tap = blockIdx.x%9, c = threadIdx.x;
  const float* w = s ? w2 : w1;
  wt[(size_t)(s*9+tap)*512 + c] = w[(size_t)c*9 + tap];
}

// ---------------- K1: v = x @ Wv (bf16), also emits xbT = bf16(x)^T ----------------
// grid 2048, block 512 (8 waves, each wave-tile 128x64), BK=32, dbuf 80KB LDS.
__global__ __launch_bounds__(512) void k_gemm_v(const float* __restrict__ x, const u16* __restrict__ WvT,
                                                u16* __restrict__ v, u16* __restrict__ xbT){
  extern __shared__ __align__(16) u16 sm[];   // A0[4096] A1[4096] B0[16384] B1[16384] u16
  const int tid = threadIdx.x;
  const int l = tid & 63, w = tid >> 6;       // 8 waves, wave w owns cols w*64..w*64+63
  const long r0 = (long)blockIdx.x * 128;
  f32x4 acc[8][4] = {};

  const int arow = tid >> 2, ac = tid & 3;    // A stage: row 0..127, k-chunk 0..3
  const float* xp = x + (r0 + arow)*512 + ac*8;
  f32x4 rAa, rAb;

  auto LOADA = [&](int kk){ rAa = *(const f32x4*)(xp + kk); rAb = *(const f32x4*)(xp + kk + 4); };
  auto WRITEA = [&](int buf){
    u16x8 o;
    o[0]=f2bf(rAa.x); o[1]=f2bf(rAa.y); o[2]=f2bf(rAa.z); o[3]=f2bf(rAa.w);
    o[4]=f2bf(rAb.x); o[5]=f2bf(rAb.y); o[6]=f2bf(rAb.z); o[7]=f2bf(rAb.w);
    *(u16x8*)&sm[buf*4096 + arow*32 + ((ac ^ ((arow>>1)&3))*8)] = o;
  };
  auto GLOADB = [&](int buf, int kk){
    #pragma unroll
    for (int i = 0; i < 4; ++i){
      int blkrow = w*64 + i*16;
      int r = blkrow + (l>>2);
      const u16* src = WvT + (size_t)r*512 + kk + (((l&3) ^ ((l>>3)&3))*8);
      gload16(src, &sm[8192 + buf*16384 + blkrow*32]);
    }
  };

  LOADA(0); WRITEA(0); LOADA(32); GLOADB(0, 0);
  __syncthreads();
  for (int t = 0; t < 16; ++t){
    const int cur = t & 1;
    if (t < 15){
      WRITEA(cur^1);
      if (t < 14) LOADA((t+2)*32);
      GLOADB(cur^1, (t+1)*32);
    }
    const u16* Al = sm + cur*4096;
    const u16* Bl = sm + 8192 + cur*16384;
    bf16x8 bfr[4];
    #pragma unroll
    for (int nf = 0; nf < 4; ++nf){
      int row = w*64 + nf*16 + (l&15);
      bfr[nf] = *(const bf16x8*)&Bl[row*32 + (((l>>4) ^ ((row>>1)&3))*8)];
    }
    #pragma unroll
    for (int mf = 0; mf < 8; ++mf){
      int row = mf*16 + (l&15);
      bf16x8 af = *(const bf16x8*)&Al[row*32 + (((l>>4) ^ ((row>>1)&3))*8)];
      #pragma unroll
      for (int nf = 0; nf < 4; ++nf)
        acc[mf][nf] = __builtin_amdgcn_mfma_f32_16x16x32_bf16(af, bfr[nf], acc[mf][nf], 0,0,0);
    }
    { // xbT write for this K-step from Al: [ch 32][tok 128]
      int chloc = tid & 31, tg = tid >> 5;    // 16 groups x 8 tok
      u16x8 o;
      #pragma unroll
      for (int j = 0; j < 8; ++j){
        int tok = tg*8 + j;
        o[j] = Al[tok*32 + (((chloc>>3) ^ ((tok>>1)&3))*8) + (chloc&7)];
      }
      *(u16x8*)(xbT + (size_t)(t*32 + chloc)*262144 + r0 + tg*8) = o;
    }
    __syncthreads();
  }
  #pragma unroll
  for (int mf = 0; mf < 8; ++mf)
    #pragma unroll
    for (int nf = 0; nf < 4; ++nf){
      int col = w*64 + nf*16 + (l&15);
      #pragma unroll
      for (int j = 0; j < 4; ++j){
        long row = r0 + mf*16 + (l>>4)*4 + j;
        v[(size_t)row*512 + col] = f2bf(acc[mf][nf][j]);
      }
    }
}

// ---------------- K0: S partials = X^T X from xbT (R19 config: BK=64, 128KB) ----
// grid 768 = b(4)*combo(3)*csplit(64); block 512 (8 waves 2x4 -> 128x64 tiles),
// BK=64, double-buffered 128KB dynamic LDS, prefetch-before-compute.
__global__ __launch_bounds__(512) void k_syrk(const u16* __restrict__ xbT, float* __restrict__ P){
  extern __shared__ __align__(16) u16 sm[];   // A0 @0, A1 @16384, B0 @32768, B1 @49152
  const int bid = blockIdx.x;
  const int cs = bid & 63, combo = (bid>>6)%3, b = bid/192;
  const int hA = (combo==2) ? 1 : 0;
  const int tid = threadIdx.x;
  const int l = tid & 63, w = tid >> 6;
  const int wi = w >> 2, wj = w & 3;          // wave tile 128 rows x 64 cols
  const long tokb0 = (long)b*65536 + (long)cs*1024;
  f32x4 acc[8][4] = {};

  auto STAGE = [&](int buf, long tokb){
    u16* Ab = sm + buf*16384;
    #pragma unroll
    for (int i = 0; i < 4; ++i){
      int blkrow = w*32 + i*8;
      int r = blkrow + (l>>3);
      gload16(xbT + (size_t)(hA*256 + r)*262144 + tokb + (((l&7) ^ ((l>>3)&7))*8), Ab + blkrow*64);
    }
    if (combo == 1){
      u16* Bb = sm + 32768 + buf*16384;
      #pragma unroll
      for (int i = 0; i < 4; ++i){
        int blkrow = w*32 + i*8;
        int r = blkrow + (l>>3);
        gload16(xbT + (size_t)(256 + r)*262144 + tokb + (((l&7) ^ ((l>>3)&7))*8), Bb + blkrow*64);
      }
    }
  };

  STAGE(0, tokb0);
  __syncthreads();
  for (int t = 0; t < 16; ++t){
    const int cur = t & 1;
    if (t < 15) STAGE(cur^1, tokb0 + (t+1)*64);
    const u16* Al = sm + cur*16384;
    const u16* Bl = (combo==1) ? (sm + 32768 + cur*16384) : Al;
    #pragma unroll
    for (int ks = 0; ks < 2; ++ks){
      bf16x8 bfr[4];
      #pragma unroll
      for (int nf = 0; nf < 4; ++nf){
        int row = wj*64 + nf*16 + (l&15);
        bfr[nf] = *(const bf16x8*)&Bl[row*64 + (((ks*4 + (l>>4)) ^ (row&7))*8)];
      }
      #pragma unroll
      for (int mf = 0; mf < 8; ++mf){
        int row = wi*128 + mf*16 + (l&15);
        bf16x8 af = *(const bf16x8*)&Al[row*64 + (((ks*4 + (l>>4)) ^ (row&7))*8)];
        #pragma unroll
        for (int nf = 0; nf < 4; ++nf)
          acc[mf][nf] = __builtin_amdgcn_mfma_f32_16x16x32_bf16(af, bfr[nf], acc[mf][nf], 0,0,0);
      }
    }
    __syncthreads();
  }
  float* Pb = P + (size_t)bid*65536;
  #pragma unroll
  for (int mf = 0; mf < 8; ++mf)
    #pragma unroll
    for (int nf = 0; nf < 4; ++nf)
      #pragma unroll
      for (int j = 0; j < 4; ++j){
        int il = wi*128 + mf*16 + (l>>4)*4 + j;
        int jl = wj*64 + nf*16 + (l&15);
        Pb[il*256 + jl] = acc[mf][nf][j];
      }
}

// reduce partials -> S[b][512][512]
__global__ void k_sred(const float* __restrict__ P, float* __restrict__ S){
  int bid = blockIdx.x;               // 3072 = 4*3*256
  int il = bid & 255, combo = (bid>>8)%3, b = bid/768;
  int hi = (combo==2)?1:0, hj = (combo==0)?0:1;
  int jl = threadIdx.x;
  float s = 0.f;
  for (int cs = 0; cs < 64; ++cs)
    s += P[((size_t)(b*192 + combo*64 + cs))*65536 + il*256 + jl];
  int I = hi*256 + il, J = hj*256 + jl;
  S[((size_t)b*512 + I)*512 + J] = s;
  if (combo == 1) S[((size_t)b*512 + J)*512 + I] = s;
}

// ---------------- tiny algebra chain ----------------
__global__ __launch_bounds__(256) void k_a1(const float* __restrict__ S, const float* __restrict__ Wq,
                                            const float* __restrict__ Wk, float* __restrict__ T, float* __restrict__ U){
  int bid = blockIdx.x;
  int b = bid>>6, rem = bid&63, which = rem>>5, rbase = (rem&31)*16;
  const float* W = which ? Wk : Wq;
  float* O = which ? U : T;
  int tid = threadIdx.x;
  int rg = tid>>6, c0 = (tid&63)*8;
  const float* Sr = S + (size_t)b*262144 + (size_t)(rbase + rg*4)*512;
  float acc[4][8] = {};
  for (int k = 0; k < 512; ++k){
    float s0 = Sr[k], s1 = Sr[512+k], s2 = Sr[1024+k], s3 = Sr[1536+k];
    f32x4 wa = *(const f32x4*)(W + (size_t)k*512 + c0);
    f32x4 wb = *(const f32x4*)(W + (size_t)k*512 + c0 + 4);
    #pragma unroll
    for (int j = 0; j < 4; ++j){
      acc[0][j]   += s0*wa[j]; acc[1][j]   += s1*wa[j]; acc[2][j]   += s2*wa[j]; acc[3][j]   += s3*wa[j];
      acc[0][4+j] += s0*wb[j]; acc[1][4+j] += s1*wb[j]; acc[2][4+j] += s2*wb[j]; acc[3][4+j] += s3*wb[j];
    }
  }
  float* Ob = O + (size_t)b*262144;
  #pragma unroll
  for (int i = 0; i < 4; ++i){
    f32x4 o0, o1;
    o0.x=acc[i][0]; o0.y=acc[i][1]; o0.z=acc[i][2]; o0.w=acc[i][3];
    o1.x=acc[i][4]; o1.y=acc[i][5]; o1.z=acc[i][6]; o1.w=acc[i][7];
    *(f32x4*)(Ob + (size_t)(rbase+rg*4+i)*512 + c0)     = o0;
    *(f32x4*)(Ob + (size_t)(rbase+rg*4+i)*512 + c0 + 4) = o1;
  }
}

__global__ void k_a2(const float* __restrict__ Wq, const float* __restrict__ Wk,
                     const float* __restrict__ T, const float* __restrict__ U,
                     float* __restrict__ G, float* __restrict__ q2, float* __restrict__ k2){
  int b = blockIdx.x>>3, h = blockIdx.x&7;
  int tid = threadIdx.x;
  int d0 = (tid>>4)*4, e0 = (tid&15)*4;
  const float* Tb = T + (size_t)b*262144;
  float acc[4][4] = {};
  for (int i = 0; i < 512; ++i){
    f32x4 wk = *(const f32x4*)(Wk + (size_t)i*512 + h*64 + d0);
    f32x4 tv = *(const f32x4*)(Tb + (size_t)i*512 + h*64 + e0);
    #pragma unroll
    for (int di = 0; di < 4; ++di)
      #pragma unroll
      for (int ej = 0; ej < 4; ++ej) acc[di][ej] += wk[di]*tv[ej];
  }
  float* Gb = G + ((size_t)(b*8+h))*4096;
  #pragma unroll
  for (int di = 0; di < 4; ++di)
    #pragma unroll
    for (int ej = 0; ej < 4; ++ej) Gb[(d0+di)*64 + e0+ej] = acc[di][ej];
  if (tid < 64){
    int e = tid; float a = 0.f;
    for (int j = 0; j < 512; ++j) a += Wq[(size_t)j*512 + h*64 + e] * Tb[(size_t)j*512 + h*64 + e];
    q2[b*512 + h*64 + e] = a;
  } else if (tid < 128){
    int d = tid - 64; float a = 0.f;
    const float* Ub = U + (size_t)b*262144;
    for (int j = 0; j < 512; ++j) a += Wk[(size_t)j*512 + h*64 + d] * Ub[(size_t)j*512 + h*64 + d];
    k2[b*512 + h*64 + d] = a;
  }
}

__global__ void k_a3(const float* __restrict__ G, const float* __restrict__ resc,
                     const float* __restrict__ q2, const float* __restrict__ k2, float* __restrict__ Aa){
  int b = blockIdx.x>>3, h = blockIdx.x&7;
  int d = threadIdx.x;
  const float* g = G + ((size_t)(b*8+h))*4096 + d*64;
  float kn = fmaxf(sqrtf(k2[b*512 + h*64 + d]), 1e-12f);
  float sc = resc[h] / kn;
  float m = -3.4e38f;
  for (int e = 0; e < 64; ++e){
    float qn = fmaxf(sqrtf(q2[b*512 + h*64 + e]), 1e-12f);
    m = fmaxf(m, g[e]*sc/qn);
  }
  float ssum = 0.f;
  for (int e = 0; e < 64; ++e){
    float qn = fmaxf(sqrtf(q2[b*512 + h*64 + e]), 1e-12f);
    ssum += expf(g[e]*sc/qn - m);
  }
  float inv = 1.0f/ssum;
  float* ao = Aa + ((size_t)(b*8+h))*4096 + d*64;
  for (int e = 0; e < 64; ++e){
    float qn = fmaxf(sqrtf(q2[b*512 + h*64 + e]), 1e-12f);
    ao[e] = expf(g[e]*sc/qn - m)*inv;
  }
}

__global__ void k_a4(const float* __restrict__ Aa, const float* __restrict__ pw, u16* __restrict__ MT){
  int bid = blockIdx.x;
  int jt = bid&3, h = (bid>>2)&7, b = bid>>5;
  int tid = threadIdx.x;
  int j = jt*128 + (tid&127), eh = tid>>7;
  const float* Ab = Aa + ((size_t)(b*8+h))*4096;
  float acc[32] = {};
  for (int d = 0; d < 64; ++d){
    float p = pw[(size_t)(h*64+d)*512 + j];
    const float* ar = Ab + d*64 + eh*32;
    #pragma unroll
    for (int q = 0; q < 8; ++q){
      f32x4 pa = *(const f32x4*)(ar + q*4);
      acc[q*4+0] += pa.x*p; acc[q*4+1] += pa.y*p; acc[q*4+2] += pa.z*p; acc[q*4+3] += pa.w*p;
    }
  }
  u16* mo = MT + (size_t)b*262144 + (size_t)j*512 + h*64 + eh*32;
  #pragma unroll
  for (int q = 0; q < 16; ++q){
    u32 pk = (u32)f2bf(acc[2*q]) | ((u32)f2bf(acc[2*q+1])<<16);
    *(u32*)&mo[2*q] = pk;
  }
}

// ---------------- fused conv v8 (R19, 314us): R15 structure + packed-f16 math ----
// grid 32768 = b(4)*ty(16)*tx(16)*chgrp(32); block 256; LDS 29KB -> 5 blk/CU.
__global__ __launch_bounds__(256) void k_conv_fused(const u16* __restrict__ v, const float* __restrict__ wt,
                                                    u16* __restrict__ cbuf){
  __shared__ __align__(16) u16 vtf[400*20];   // 20x20 spatial x (16ch + 4 pad) f16 bits
  __shared__ __align__(16) u16 t1f[324*20];   // 18x18 spatial x (16ch + 4 pad) f16 bits
  const int logical = (blockIdx.x & 7)*4096 + (blockIdx.x >> 3);  // XCD-chunked
  const int g = logical & 31, tx = (logical>>5)&15, ty = (logical>>9)&15, b = logical>>13;
  const int c0 = g*16, oy0 = ty*16, ox0 = tx*16;
  const int tid = threadIdx.x;
  const int quad = tid & 3;

  // stage v 20x20x16 -> f16 LDS (bf16->f32->pk f16), zero outside image
  for (int k = 0; k < 7; ++k){
    int q = tid + k*256; if (q >= 1600) break;
    int pos = q >> 2;
    int ly = pos / 20, lx = pos - ly*20;
    int gy = oy0 - 2 + ly, gx = ox0 - 2 + lx;
    u32x2 st = {};
    if (gy >= 0 && gy < 256 && gx >= 0 && gx < 256){
      u16x4 raw = *(const u16x4*)(v + ((size_t)(b*65536 + gy*256 + gx))*512 + c0 + quad*4);
      st.x = asU32(pkh(bf2f(raw[0]), bf2f(raw[1])));
      st.y = asU32(pkh(bf2f(raw[2]), bf2f(raw[3])));
    }
    *(u32x2*)&vtf[pos*20 + quad*4] = st;
  }

  h2 wql[9], wqh[9];
  #pragma unroll
  for (int tap = 0; tap < 9; ++tap){
    f32x4 wf = *(const f32x4*)(wt + (size_t)tap*512 + c0 + quad*4);
    wql[tap] = pkh(wf.x, wf.y); wqh[tap] = pkh(wf.z, wf.w);
  }
  __syncthreads();

  // conv1+gelu on 18x18, y-blocked (4 outputs/task over 6 rows x 3 cols).
  for (int task = tid; task < 1440; task += 256){
    int tq = task & 3;                  // == quad
    int rest = task >> 2;
    if (rest >= 90) break;
    int x1 = rest % 18, ychunk = rest / 18;
    int y1b = ychunk*4;
    h2 accl[4] = {}, acch[4] = {};
    #pragma unroll
    for (int rr = 0; rr < 6; ++rr){
      int yr = y1b + rr; yr = yr > 19 ? 19 : yr;   // clamp feeds only unstored outputs
      u32x2 r0 = *(const u32x2*)&vtf[(yr*20 + x1    )*20 + tq*4];
      u32x2 r1 = *(const u32x2*)&vtf[(yr*20 + x1 + 1)*20 + tq*4];
      u32x2 r2 = *(const u32x2*)&vtf[(yr*20 + x1 + 2)*20 + tq*4];
      h2 a0l = asH2(r0.x), a0h = asH2(r0.y);
      h2 a1l = asH2(r1.x), a1h = asH2(r1.y);
      h2 a2l = asH2(r2.x), a2h = asH2(r2.y);
      #pragma unroll
      for (int oy = 0; oy < 4; ++oy){
        int dy = rr - oy;
        if (dy >= 0 && dy < 3){
          accl[oy] += a0l*wql[dy*3+0] + a1l*wql[dy*3+1] + a2l*wql[dy*3+2];
          acch[oy] += a0h*wqh[dy*3+0] + a1h*wqh[dy*3+1] + a2h*wqh[dy*3+2];
        }
      }
    }
    #pragma unroll
    for (int oy = 0; oy < 4; ++oy){
      int y1 = y1b + oy;
      if (y1 < 18){
        int gy1 = oy0 - 1 + y1, gx1 = ox0 - 1 + x1;
        bool inimg = (gy1 >= 0 && gy1 < 256 && gx1 >= 0 && gx1 < 256);
        float a0 = (float)accl[oy][0], a1 = (float)accl[oy][1];
        float a2 = (float)acch[oy][0], a3 = (float)acch[oy][1];
        float g0 = a0 / (1.0f + __expf(-1.5957691216f*a0*(1.0f + 0.044715f*a0*a0)));
        float g1 = a1 / (1.0f + __expf(-1.5957691216f*a1*(1.0f + 0.044715f*a1*a1)));
        float g2 = a2 / (1.0f + __expf(-1.5957691216f*a2*(1.0f + 0.044715f*a2*a2)));
        float g3 = a3 / (1.0f + __expf(-1.5957691216f*a3*(1.0f + 0.044715f*a3*a3)));
        u32x2 st = {};
        if (inimg){ st.x = asU32(pkh(g0, g1)); st.y = asU32(pkh(g2, g3)); }
        *(u32x2*)&t1f[(y1*18 + x1)*20 + tq*4] = st;
      }
    }
  }

  #pragma unroll
  for (int tap = 0; tap < 9; ++tap){
    f32x4 wf = *(const f32x4*)(wt + (size_t)(9+tap)*512 + c0 + quad*4);
    wql[tap] = pkh(wf.x, wf.y); wqh[tap] = pkh(wf.z, wf.w);
  }
  __syncthreads();

  // conv2 on 16x16, y-blocked: exactly 256 tasks = x2(16, fastest) x ychunk(4) x quad
  {
    int rest = tid >> 2;                // quad == tid&3
    int x2 = rest & 15, ychunk = rest >> 4;
    int y2b = ychunk*4;
    h2 accl[4] = {}, acch[4] = {};
    #pragma unroll
    for (int rr = 0; rr < 6; ++rr){
      int yr = y2b + rr;                // max 12+5=17 <= 17: in range
      u32x2 r0 = *(const u32x2*)&t1f[(yr*18 + x2    )*20 + quad*4];
      u32x2 r1 = *(const u32x2*)&t1f[(yr*18 + x2 + 1)*20 + quad*4];
      u32x2 r2 = *(const u32x2*)&t1f[(yr*18 + x2 + 2)*20 + quad*4];
      h2 a0l = asH2(r0.x), a0h = asH2(r0.y);
      h2 a1l = asH2(r1.x), a1h = asH2(r1.y);
      h2 a2l = asH2(r2.x), a2h = asH2(r2.y);
      #pragma unroll
      for (int oy = 0; oy < 4; ++oy){
        int dy = rr - oy;
        if (dy >= 0 && dy < 3){
          accl[oy] += a0l*wql[dy*3+0] + a1l*wql[dy*3+1] + a2l*wql[dy*3+2];
          acch[oy] += a0h*wqh[dy*3+0] + a1h*wqh[dy*3+1] + a2h*wqh[dy*3+2];
        }
      }
    }
    #pragma unroll
    for (int oy = 0; oy < 4; ++oy){
      u16x4 o;
      o[0] = f2bf((float)accl[oy][0]); o[1] = f2bf((float)accl[oy][1]);
      o[2] = f2bf((float)acch[oy][0]); o[3] = f2bf((float)acch[oy][1]);
      size_t tok = (size_t)b*65536 + (size_t)(oy0 + y2b + oy)*256 + (ox0 + x2);
      *(u16x4*)(cbuf + tok*512 + c0 + quad*4) = o;
    }
  }
}

// ---------------- K4: out = v @ M[b] + pb + cbuf ----------------
// 256x256 block tile, 512 thr = 8 waves of 128x64, BK=64,
// double-buffered 128KB dynamic LDS, prefetch-before-compute.
__global__ __launch_bounds__(512, 2) void k_gemm_out(const u16* __restrict__ v, const u16* __restrict__ MT,
                                                     const float* __restrict__ proj_b, const u16* __restrict__ cbuf,
                                                     float* __restrict__ out){
  extern __shared__ __align__(16) u16 sm[];
  const int tid = threadIdx.x;
  const int l = tid & 63, w = tid >> 6;       // 8 waves
  const int wr = w >> 2, wc = w & 3;          // 2 x 4 -> wave tile 128x64
  const int bid = blockIdx.x;
  const int wg = (bid & 7)*256 + (bid >> 3);  // XCD-contiguous chunks (bijective)
  const long r0 = (long)(wg >> 1) * 256;
  const int  c0b = (wg & 1) * 256;
  const int  b = (int)(r0 >> 16);
  const u16* Mb = MT + (size_t)b*262144;
  f32x4 acc[8][4] = {};

  auto STAGE = [&](int buf, int k0){
    u16* Ab = sm + buf*16384;
    u16* Bb = sm + 32768 + buf*16384;
    #pragma unroll
    for (int i = 0; i < 4; ++i){
      int blkrow = w*32 + i*8;
      int r = blkrow + (l>>3);
      gload16(v + (size_t)(r0 + r)*512 + k0 + (((l&7) ^ (r&7))*8), Ab + blkrow*64);
    }
    #pragma unroll
    for (int i = 0; i < 4; ++i){
      int blkrow = w*32 + i*8;
      int r = blkrow + (l>>3);
      gload16(Mb + (size_t)(c0b + r)*512 + k0 + (((l&7) ^ (r&7))*8), Bb + blkrow*64);
    }
  };

  STAGE(0, 0);
  __syncthreads();
  for (int t = 0; t < 8; ++t){
    const int cur = t & 1;
    if (t < 7) STAGE(cur^1, (t+1)*64);
    const u16* Al = sm + cur*16384;
    const u16* Bl = sm + 32768 + cur*16384;
    #pragma unroll
    for (int ks = 0; ks < 2; ++ks){
      bf16x8 bfr[4];
      #pragma unroll
      for (int nf = 0; nf < 4; ++nf){
        int row = wc*64 + nf*16 + (l&15);
        bfr[nf] = *(const bf16x8*)&Bl[row*64 + (((ks*4 + (l>>4)) ^ (row&7))*8)];
      }
      #pragma unroll
      for (int mf = 0; mf < 8; ++mf){
        int row = wr*128 + mf*16 + (l&15);
        bf16x8 af = *(const bf16x8*)&Al[row*64 + (((ks*4 + (l>>4)) ^ (row&7))*8)];
        #pragma unroll
        for (int nf = 0; nf < 4; ++nf)
          acc[mf][nf] = __builtin_amdgcn_mfma_f32_16x16x32_bf16(af, bfr[nf], acc[mf][nf], 0,0,0);
      }
    }
    __syncthreads();
  }
  #pragma unroll
  for (int mf = 0; mf < 8; ++mf)
    #pragma unroll
    for (int nf = 0; nf < 4; ++nf){
      int col = c0b + wc*64 + nf*16 + (l&15);
      float pb = proj_b[col];
      #pragma unroll
      for (int j = 0; j < 4; ++j){
        long row = r0 + wr*128 + mf*16 + (l>>4)*4 + j;
        out[(size_t)row*512 + col] = acc[mf][nf][j] + pb + bf2f(cbuf[(size_t)row*512 + col]);
      }
    }
}

// ---------------- host ----------------
extern "C" void kernel_launch(void* const* d_in, const int* in_sizes, int n_in,
                              void* d_out, int out_size, void* d_ws, size_t ws_size,
                              hipStream_t stream){
  const float* x   = (const float*)d_in[0];
  const float* Wq  = (const float*)d_in[1];
  const float* Wk  = (const float*)d_in[2];
  const float* Wv  = (const float*)d_in[3];
  const float* rsc = (const float*)d_in[4];
  const float* pw  = (const float*)d_in[5];
  const float* pb  = (const float*)d_in[6];
  const float* w1  = (const float*)d_in[7];
  const float* w2  = (const float*)d_in[8];
  float* out = (float*)d_out;
  char* ws = (char*)d_ws;

  const size_t MB256 = 268435456;
  u16*   v    = (u16*)ws;                   // 256MB, live whole call
  u16*   xbT  = (u16*)(ws + MB256);         // 256MB, dead after k_syrk
  u16*   cbuf = xbT;                        // aliases xbT (conv runs after syrk)
  char*  sm0  = ws + 2*MB256;
  float* P    = (float*)d_out;              // 192MB partials in d_out (dead before out written)

  float* S   = (float*)(sm0);
  float* Tm  = (float*)(sm0 + 4194304);
  float* Um  = (float*)(sm0 + 8388608);
  float* G   = (float*)(sm0 + 12582912);
  float* Aa  = (float*)(sm0 + 13107200);
  float* q2  = (float*)(sm0 + 13631488);
  float* k2  = (float*)(sm0 + 13639680);
  u16*   MT  = (u16*)  (sm0 + 13647872);
  u16*   WvT = (u16*)  (sm0 + 15745024);
  float* wt  = (float*)(sm0 + 16269312);

  k_wvt <<<512, 256, 0, stream>>>(Wv, WvT);
  k_wrep<<<18, 512, 0, stream>>>(w1, w2, wt);
  k_gemm_v<<<2048, 512, 81920, stream>>>(x, WvT, v, xbT);
  k_syrk<<<768, 512, 131072, stream>>>(xbT, P);
  k_sred<<<3072, 256, 0, stream>>>(P, S);
  k_a1<<<256, 256, 0, stream>>>(S, Wq, Wk, Tm, Um);
  k_a2<<<32, 256, 0, stream>>>(Wq, Wk, Tm, Um, G, q2, k2);
  k_a3<<<32, 64, 0, stream>>>(G, rsc, q2, k2, Aa);
  k_a4<<<128, 256, 0, stream>>>(Aa, pw, MT);
  k_conv_fused<<<32768, 256, 0, stream>>>(v, wt, cbuf);
  k_gemm_out<<<2048, 512, 131072, stream>>>(v, MT, pb, cbuf, out);
}